// Round 1
// baseline (160.463 us; speedup 1.0000x reference)
//
#include <hip/hip_runtime.h>

// Problem constants (from reference)
#define S 7
#define BB 2
#define CLS 20
#define NCELLS (8192 * S * S)        // 401408
#define CPB 256                      // cells per block
#define THREADS 256
#define PRED_F 30                    // BB*5 + CLS
#define TGT_F 25                     // CLS + 5

__device__ __forceinline__ float iou_fn(float ax, float ay, float aw, float ah,
                                        float bx, float by, float bw, float bh) {
    float ax1 = ax - aw * 0.5f, ay1 = ay - ah * 0.5f;
    float ax2 = ax + aw * 0.5f, ay2 = ay + ah * 0.5f;
    float bx1 = bx - bw * 0.5f, by1 = by - bh * 0.5f;
    float bx2 = bx + bw * 0.5f, by2 = by + bh * 0.5f;
    float iw = fmaxf(fminf(ax2, bx2) - fmaxf(ax1, bx1), 0.0f);
    float ih = fmaxf(fminf(ay2, by2) - fmaxf(ay1, by1), 0.0f);
    float inter = iw * ih;
    float uni = fabsf(aw * ah) + fabsf(bw * bh) - inter;
    return inter / (uni + 1e-6f);
}

__global__ __launch_bounds__(THREADS) void yolo_main(const float* __restrict__ pred,
                                                     const float* __restrict__ tgt,
                                                     float* __restrict__ acc) {
    __shared__ float lp[CPB * PRED_F];   // 30720 B
    __shared__ float lt[CPB * TGT_F];    // 25600 B
    __shared__ float red[3][THREADS / 64];

    const int b = blockIdx.x;
    const int t = threadIdx.x;

    // Coalesced float4 staging: chunk bases are 16B-aligned (30720 / 25600 byte strides)
    const float4* gp = (const float4*)(pred + (size_t)b * (CPB * PRED_F));
    float4* sp = (float4*)lp;
    #pragma unroll
    for (int i = 0; i < (CPB * PRED_F / 4 + THREADS - 1) / THREADS; ++i) {
        int idx = t + i * THREADS;
        if (idx < CPB * PRED_F / 4) sp[idx] = gp[idx];
    }
    const float4* gt = (const float4*)(tgt + (size_t)b * (CPB * TGT_F));
    float4* st = (float4*)lt;
    #pragma unroll
    for (int i = 0; i < (CPB * TGT_F / 4 + THREADS - 1) / THREADS; ++i) {
        int idx = t + i * THREADS;
        if (idx < CPB * TGT_F / 4) st[idx] = gt[idx];
    }
    __syncthreads();

    const float* pp = lp + t * PRED_F;
    const float* tp = lt + t * TGT_F;

    float tconf = tp[CLS + 0];
    float tx = tp[CLS + 1], ty = tp[CLS + 2], tw = tp[CLS + 3], th = tp[CLS + 4];

    float iou0 = iou_fn(pp[CLS + 1], pp[CLS + 2], pp[CLS + 3], pp[CLS + 4], tx, ty, tw, th);
    float iou1 = iou_fn(pp[CLS + 6], pp[CLS + 7], pp[CLS + 8], pp[CLS + 9], tx, ty, tw, th);
    // jnp.argmax takes FIRST max on ties -> box 1 only on strict greater
    int sel = (iou1 > iou0) ? 1 : 0;
    float iou_best = fmaxf(iou0, iou1);

    const float* pb = pp + CLS + sel * 5;
    float dx = tx - pb[1], dy = ty - pb[2];
    float center = dx * dx + dy * dy;
    float dw = sqrtf(tw) - sqrtf(fabsf(pb[3]));
    float dh = sqrtf(th) - sqrtf(fabsf(pb[4]));
    float wh = dw * dw + dh * dh;
    float dc = tconf - pb[0];
    float conf_sq = dc * dc;

    float cls_sq = 0.0f;
    #pragma unroll
    for (int k = 0; k < CLS; ++k) {
        float d = pp[k] - tp[k];
        cls_sq += d * d;
    }

    float objf = (tconf == 1.0f) ? 1.0f : 0.0f;
    float loss = objf * (5.0f * (center + wh) + conf_sq + cls_sq)
               + (1.0f - objf) * 0.5f * conf_sq;
    float iou_o = objf * iou_best;

    // wave (64-lane) shuffle reduction
    #pragma unroll
    for (int off = 32; off > 0; off >>= 1) {
        loss  += __shfl_down(loss,  off, 64);
        iou_o += __shfl_down(iou_o, off, 64);
        objf  += __shfl_down(objf,  off, 64);
    }
    const int wave = t >> 6, lane = t & 63;
    if (lane == 0) {
        red[0][wave] = loss;
        red[1][wave] = iou_o;
        red[2][wave] = objf;
    }
    __syncthreads();
    if (t == 0) {
        float l = 0.f, i = 0.f, o = 0.f;
        #pragma unroll
        for (int w = 0; w < THREADS / 64; ++w) {
            l += red[0][w];
            i += red[1][w];
            o += red[2][w];
        }
        atomicAdd(&acc[0], l);
        atomicAdd(&acc[1], i);
        atomicAdd(&acc[2], o);
    }
}

__global__ void yolo_fin(const float* __restrict__ acc, float* __restrict__ out) {
    out[0] = acc[0];
    out[1] = acc[1] / fmaxf(acc[2], 1.0f);
}

extern "C" void kernel_launch(void* const* d_in, const int* in_sizes, int n_in,
                              void* d_out, int out_size, void* d_ws, size_t ws_size,
                              hipStream_t stream) {
    const float* pred = (const float*)d_in[0];
    const float* tgt  = (const float*)d_in[1];
    float* out = (float*)d_out;
    float* acc = (float*)d_ws;

    hipMemsetAsync(d_ws, 0, 3 * sizeof(float), stream);
    yolo_main<<<NCELLS / CPB, THREADS, 0, stream>>>(pred, tgt, acc);
    yolo_fin<<<1, 1, 0, stream>>>(acc, out);
}

// Round 2
// 125.856 us; speedup vs baseline: 1.2750x; 1.2750x over previous
//
#include <hip/hip_runtime.h>

// Problem constants (from reference)
#define S 7
#define BB 2
#define CLS 20
#define NCELLS (8192 * S * S)        // 401408
#define CPB 64                       // cells per block == threads per block (1 wave)
#define THREADS 64
#define NBLK (NCELLS / CPB)          // 6272
#define PRED_F 30                    // BB*5 + CLS
#define TGT_F 25                     // CLS + 5

// Per-block staging sizes in float4 units
#define PRED_Q (CPB * PRED_F / 4)    // 480
#define TGT_Q  (CPB * TGT_F / 4)     // 400

__device__ __forceinline__ float iou_fn(float ax, float ay, float aw, float ah,
                                        float bx, float by, float bw, float bh) {
    float ax1 = ax - aw * 0.5f, ay1 = ay - ah * 0.5f;
    float ax2 = ax + aw * 0.5f, ay2 = ay + ah * 0.5f;
    float bx1 = bx - bw * 0.5f, by1 = by - bh * 0.5f;
    float bx2 = bx + bw * 0.5f, by2 = by + bh * 0.5f;
    float iw = fmaxf(fminf(ax2, bx2) - fmaxf(ax1, bx1), 0.0f);
    float ih = fmaxf(fminf(ay2, by2) - fmaxf(ay1, by1), 0.0f);
    float inter = iw * ih;
    float uni = fabsf(aw * ah) + fabsf(bw * bh) - inter;
    return inter / (uni + 1e-6f);
}

// One wave per block: no __syncthreads coupling across waves, ~11 blocks/CU
// (LDS 14.08 KB/block), each wave independently pipelines stage->compute->reduce.
__global__ __launch_bounds__(THREADS) void yolo_main(const float* __restrict__ pred,
                                                     const float* __restrict__ tgt,
                                                     float* __restrict__ pl,
                                                     float* __restrict__ pi,
                                                     float* __restrict__ po) {
    __shared__ float lp[CPB * PRED_F];   // 7680 B
    __shared__ float lt[CPB * TGT_F];    // 6400 B

    const int b = blockIdx.x;
    const int t = threadIdx.x;           // == lane (single wave)

    // Coalesced float4 staging. Block chunk bases are 16B-aligned:
    // pred chunk stride = 64*30*4 = 7680 B, tgt chunk stride = 64*25*4 = 6400 B.
    const float4* gp = (const float4*)(pred + (size_t)b * (CPB * PRED_F));
    float4* sp = (float4*)lp;
    #pragma unroll
    for (int i = 0; i < (PRED_Q + THREADS - 1) / THREADS; ++i) {   // 8 iters (7.5)
        int idx = t + i * THREADS;
        if (idx < PRED_Q) sp[idx] = gp[idx];
    }
    const float4* gt = (const float4*)(tgt + (size_t)b * (CPB * TGT_F));
    float4* st = (float4*)lt;
    #pragma unroll
    for (int i = 0; i < (TGT_Q + THREADS - 1) / THREADS; ++i) {    // 7 iters (6.25)
        int idx = t + i * THREADS;
        if (idx < TGT_Q) st[idx] = gt[idx];
    }
    __syncthreads();   // single wave: compiles to waitcnt + cheap s_barrier

    const float* pp = lp + t * PRED_F;
    const float* tp = lt + t * TGT_F;

    float tconf = tp[CLS + 0];
    float tx = tp[CLS + 1], ty = tp[CLS + 2], tw = tp[CLS + 3], th = tp[CLS + 4];

    float iou0 = iou_fn(pp[CLS + 1], pp[CLS + 2], pp[CLS + 3], pp[CLS + 4], tx, ty, tw, th);
    float iou1 = iou_fn(pp[CLS + 6], pp[CLS + 7], pp[CLS + 8], pp[CLS + 9], tx, ty, tw, th);
    // jnp.argmax takes FIRST max on ties -> box 1 only on strict greater
    int sel = (iou1 > iou0) ? 1 : 0;
    float iou_best = fmaxf(iou0, iou1);

    const float* pb = pp + CLS + sel * 5;
    float dx = tx - pb[1], dy = ty - pb[2];
    float center = dx * dx + dy * dy;
    float dw = sqrtf(tw) - sqrtf(fabsf(pb[3]));
    float dh = sqrtf(th) - sqrtf(fabsf(pb[4]));
    float wh = dw * dw + dh * dh;
    float dc = tconf - pb[0];
    float conf_sq = dc * dc;

    float cls_sq = 0.0f;
    #pragma unroll
    for (int k = 0; k < CLS; ++k) {
        float d = pp[k] - tp[k];
        cls_sq += d * d;
    }

    float objf = (tconf == 1.0f) ? 1.0f : 0.0f;
    float loss = objf * (5.0f * (center + wh) + conf_sq + cls_sq)
               + (1.0f - objf) * 0.5f * conf_sq;
    float iou_o = objf * iou_best;

    // 64-lane shuffle reduction, then ONE partial write per block (no atomics).
    #pragma unroll
    for (int off = 32; off > 0; off >>= 1) {
        loss  += __shfl_down(loss,  off, 64);
        iou_o += __shfl_down(iou_o, off, 64);
        objf  += __shfl_down(objf,  off, 64);
    }
    if (t == 0) {
        pl[b] = loss;
        pi[b] = iou_o;
        po[b] = objf;
    }
}

__global__ __launch_bounds__(256) void yolo_fin(const float* __restrict__ pl,
                                                const float* __restrict__ pi,
                                                const float* __restrict__ po,
                                                float* __restrict__ out) {
    __shared__ float red[3][256 / 64];
    float l = 0.f, i = 0.f, o = 0.f;
    for (int k = threadIdx.x; k < NBLK; k += 256) {
        l += pl[k];
        i += pi[k];
        o += po[k];
    }
    #pragma unroll
    for (int off = 32; off > 0; off >>= 1) {
        l += __shfl_down(l, off, 64);
        i += __shfl_down(i, off, 64);
        o += __shfl_down(o, off, 64);
    }
    const int wave = threadIdx.x >> 6, lane = threadIdx.x & 63;
    if (lane == 0) {
        red[0][wave] = l;
        red[1][wave] = i;
        red[2][wave] = o;
    }
    __syncthreads();
    if (threadIdx.x == 0) {
        float L = 0.f, I = 0.f, O = 0.f;
        #pragma unroll
        for (int w = 0; w < 4; ++w) {
            L += red[0][w];
            I += red[1][w];
            O += red[2][w];
        }
        out[0] = L;
        out[1] = I / fmaxf(O, 1.0f);
    }
}

extern "C" void kernel_launch(void* const* d_in, const int* in_sizes, int n_in,
                              void* d_out, int out_size, void* d_ws, size_t ws_size,
                              hipStream_t stream) {
    const float* pred = (const float*)d_in[0];
    const float* tgt  = (const float*)d_in[1];
    float* out = (float*)d_out;

    // Workspace layout (SoA for coalesced finalize reads): 3 * NBLK floats = 75 KB
    float* pl = (float*)d_ws;
    float* pi = pl + NBLK;
    float* po = pi + NBLK;

    yolo_main<<<NBLK, THREADS, 0, stream>>>(pred, tgt, pl, pi, po);
    yolo_fin<<<1, 256, 0, stream>>>(pl, pi, po, out);
}

// Round 3
// 106.348 us; speedup vs baseline: 1.5089x; 1.1834x over previous
//
#include <hip/hip_runtime.h>
#include <stdint.h>

// Problem constants (from reference)
#define S 7
#define BB 2
#define CLS 20
#define NCELLS (8192 * S * S)        // 401408
#define CPB 64                       // cells per block == threads per block (1 wave)
#define THREADS 64
#define NBLK (NCELLS / CPB)          // 6272
#define PRED_F 30                    // BB*5 + CLS
#define TGT_F 25                     // CLS + 5

// Async 16B-per-lane global->LDS copy. LDS dest = wave-uniform base + lane*16
// (m104 semantics) -- our contiguous chunk layout matches exactly.
#define ASYNC_CP16(gsrc, ldst)                                                  \
    __builtin_amdgcn_global_load_lds(                                           \
        (const __attribute__((address_space(1))) void*)(gsrc),                  \
        (__attribute__((address_space(3))) void*)(ldst), 16, 0, 0)

__device__ __forceinline__ float iou_fn(float ax, float ay, float aw, float ah,
                                        float bx, float by, float bw, float bh) {
    float ax1 = ax - aw * 0.5f, ay1 = ay - ah * 0.5f;
    float ax2 = ax + aw * 0.5f, ay2 = ay + ah * 0.5f;
    float bx1 = bx - bw * 0.5f, by1 = by - bh * 0.5f;
    float bx2 = bx + bw * 0.5f, by2 = by + bh * 0.5f;
    float iw = fmaxf(fminf(ax2, bx2) - fmaxf(ax1, bx1), 0.0f);
    float ih = fmaxf(fminf(ay2, by2) - fmaxf(ay1, by1), 0.0f);
    float inter = iw * ih;
    float uni = fabsf(aw * ah) + fabsf(bw * bh) - inter;
    return inter / (uni + 1e-6f);
}

// One wave per block (no inter-wave barrier coupling), ~11 blocks/CU (14.08 KB LDS).
// Staging via global_load_lds dwordx4: no VGPR round-trip, no ds_writes.
__global__ __launch_bounds__(THREADS) void yolo_main(const float* __restrict__ pred,
                                                     const float* __restrict__ tgt,
                                                     float4* __restrict__ part) {
    __shared__ float lp[CPB * PRED_F];   // 7680 B = 1920 floats
    __shared__ float lt[CPB * TGT_F];    // 6400 B = 1600 floats

    const int b = blockIdx.x;
    const int t = threadIdx.x;           // == lane (single wave)

    // pred chunk: 7680 B = 7 full 1024B wave-rounds + 512B tail (lanes 0..31)
    const float* gp = pred + (size_t)b * (CPB * PRED_F) + t * 4;  // per-lane 16B slot
    #pragma unroll
    for (int i = 0; i < 7; ++i) {
        ASYNC_CP16(gp + i * 256, lp + i * 256);
    }
    if (t < 32) {
        ASYNC_CP16(gp + 7 * 256, lp + 7 * 256);
    }
    // tgt chunk: 6400 B = 6 full 1024B wave-rounds + 256B tail (lanes 0..15)
    const float* gt = tgt + (size_t)b * (CPB * TGT_F) + t * 4;
    #pragma unroll
    for (int i = 0; i < 6; ++i) {
        ASYNC_CP16(gt + i * 256, lt + i * 256);
    }
    if (t < 16) {
        ASYNC_CP16(gt + 6 * 256, lt + 6 * 256);
    }
    __syncthreads();   // drains vmcnt (global_load_lds) before LDS reads

    const float* pp = lp + t * PRED_F;
    const float* tp = lt + t * TGT_F;

    float tconf = tp[CLS + 0];
    float tx = tp[CLS + 1], ty = tp[CLS + 2], tw = tp[CLS + 3], th = tp[CLS + 4];

    float iou0 = iou_fn(pp[CLS + 1], pp[CLS + 2], pp[CLS + 3], pp[CLS + 4], tx, ty, tw, th);
    float iou1 = iou_fn(pp[CLS + 6], pp[CLS + 7], pp[CLS + 8], pp[CLS + 9], tx, ty, tw, th);
    // jnp.argmax takes FIRST max on ties -> box 1 only on strict greater
    int sel = (iou1 > iou0) ? 1 : 0;
    float iou_best = fmaxf(iou0, iou1);

    const float* pb = pp + CLS + sel * 5;
    float dx = tx - pb[1], dy = ty - pb[2];
    float center = dx * dx + dy * dy;
    float dw = sqrtf(tw) - sqrtf(fabsf(pb[3]));
    float dh = sqrtf(th) - sqrtf(fabsf(pb[4]));
    float wh = dw * dw + dh * dh;
    float dc = tconf - pb[0];
    float conf_sq = dc * dc;

    float cls_sq = 0.0f;
    #pragma unroll
    for (int k = 0; k < CLS; ++k) {
        float d = pp[k] - tp[k];
        cls_sq += d * d;
    }

    float objf = (tconf == 1.0f) ? 1.0f : 0.0f;
    float loss = objf * (5.0f * (center + wh) + conf_sq + cls_sq)
               + (1.0f - objf) * 0.5f * conf_sq;
    float iou_o = objf * iou_best;

    // 64-lane shuffle reduction, then ONE float4 partial store per block.
    #pragma unroll
    for (int off = 32; off > 0; off >>= 1) {
        loss  += __shfl_down(loss,  off, 64);
        iou_o += __shfl_down(iou_o, off, 64);
        objf  += __shfl_down(objf,  off, 64);
    }
    if (t == 0) {
        part[b] = make_float4(loss, iou_o, objf, 0.0f);
    }
}

__global__ __launch_bounds__(1024) void yolo_fin(const float4* __restrict__ part,
                                                 float* __restrict__ out) {
    __shared__ float red[3][1024 / 64];
    float l = 0.f, i = 0.f, o = 0.f;
    for (int k = threadIdx.x; k < NBLK; k += 1024) {
        float4 v = part[k];
        l += v.x;
        i += v.y;
        o += v.z;
    }
    #pragma unroll
    for (int off = 32; off > 0; off >>= 1) {
        l += __shfl_down(l, off, 64);
        i += __shfl_down(i, off, 64);
        o += __shfl_down(o, off, 64);
    }
    const int wave = threadIdx.x >> 6, lane = threadIdx.x & 63;
    if (lane == 0) {
        red[0][wave] = l;
        red[1][wave] = i;
        red[2][wave] = o;
    }
    __syncthreads();
    if (threadIdx.x == 0) {
        float L = 0.f, I = 0.f, O = 0.f;
        #pragma unroll
        for (int w = 0; w < 1024 / 64; ++w) {
            L += red[0][w];
            I += red[1][w];
            O += red[2][w];
        }
        out[0] = L;
        out[1] = I / fmaxf(O, 1.0f);
    }
}

extern "C" void kernel_launch(void* const* d_in, const int* in_sizes, int n_in,
                              void* d_out, int out_size, void* d_ws, size_t ws_size,
                              hipStream_t stream) {
    const float* pred = (const float*)d_in[0];
    const float* tgt  = (const float*)d_in[1];
    float* out = (float*)d_out;
    float4* part = (float4*)d_ws;   // NBLK float4 partials = 100 KB (no init needed)

    yolo_main<<<NBLK, THREADS, 0, stream>>>(pred, tgt, part);
    yolo_fin<<<1, 1024, 0, stream>>>(part, out);
}